// Round 6
// baseline (1762.007 us; speedup 1.0000x reference)
//
#include <hip/hip_runtime.h>

#define NUM_USERS_C 500000
#define EPS_F 1e-12f

// ---------------------------------------------------------------------------
// Pass 1 over edges: self-loop flags + per-dest count. The counting atomic's
// return value IS the CSR slot -> store it so scatter needs no atomics.
// ---------------------------------------------------------------------------
__global__ void k_edgeprep(const int* __restrict__ row, const int* __restrict__ col,
                           int* __restrict__ flags, int* __restrict__ cnt,
                           int* __restrict__ slot, int E) {
    int e = blockIdx.x * blockDim.x + threadIdx.x;
    if (e < E) {
        int r = row[e], c = col[e];
        if (r == c) flags[r] = 1;          // benign race, all store 1
        slot[e] = atomicAdd(&cnt[c], 1);   // slot within dest node's CSR row
    }
}

// ---------------------------------------------------------------------------
// Two-level exclusive scan: cnt[0..N) -> rowptr[0..N]
// ---------------------------------------------------------------------------
__global__ __launch_bounds__(256) void k_blocksum(const int* __restrict__ cnt,
                                                  int* __restrict__ bsum, int N) {
    __shared__ int s[256];
    int i = blockIdx.x * 256 + threadIdx.x;
    s[threadIdx.x] = (i < N) ? cnt[i] : 0;
    __syncthreads();
    for (int d = 128; d > 0; d >>= 1) {
        if (threadIdx.x < d) s[threadIdx.x] += s[threadIdx.x + d];
        __syncthreads();
    }
    if (threadIdx.x == 0) bsum[blockIdx.x] = s[0];
}

// Single block: exclusive scan of NB (<=1024) block sums; also writes rowptr[N].
__global__ __launch_bounds__(1024) void k_scanbsum(const int* __restrict__ bsum,
                                                   int* __restrict__ boff,
                                                   int* __restrict__ rowptr,
                                                   int NB, int N) {
    __shared__ int s[1024];
    int t = threadIdx.x;
    int v = (t < NB) ? bsum[t] : 0;
    s[t] = v;
    __syncthreads();
    for (int d = 1; d < 1024; d <<= 1) {
        int u = (t >= d) ? s[t - d] : 0;
        __syncthreads();
        s[t] += u;
        __syncthreads();
    }
    if (t < NB) boff[t] = s[t] - v;       // exclusive prefix of block sums
    if (t == 1023) rowptr[N] = s[1023];   // grand total
}

__global__ __launch_bounds__(256) void k_rowptr(const int* __restrict__ cnt,
                                                const int* __restrict__ boff,
                                                int* __restrict__ rowptr, int N) {
    __shared__ int s[256];
    int i = blockIdx.x * 256 + threadIdx.x;
    int v = (i < N) ? cnt[i] : 0;
    s[threadIdx.x] = v;
    __syncthreads();
    for (int d = 1; d < 256; d <<= 1) {
        int u = (threadIdx.x >= d) ? s[threadIdx.x - d] : 0;
        __syncthreads();
        s[threadIdx.x] += u;
        __syncthreads();
    }
    if (i < N) rowptr[i] = boff[blockIdx.x] + s[threadIdx.x] - v;  // exclusive
}

// Scatter edges into CSR order (atomic-free): emeta[pos] = {src_row, raw_w}
__global__ void k_scatter(const int* __restrict__ row, const int* __restrict__ col,
                          const float* __restrict__ w, const int* __restrict__ slot,
                          const int* __restrict__ rowptr,
                          int2* __restrict__ emeta, int E) {
    int e = blockIdx.x * blockDim.x + threadIdx.x;
    if (e < E) {
        int c = col[e];
        int pos = rowptr[c] + slot[e];
        emeta[pos] = make_int2(row[e], __float_as_int(w[e]));
    }
}

// Weighted degree from CSR (coalesced, atomic-free) -> dinfo = {dinv, loop_w}
__global__ __launch_bounds__(256) void k_deg(const int* __restrict__ rowptr,
                                             const int2* __restrict__ emeta,
                                             const int* __restrict__ flags,
                                             float2* __restrict__ dinfo, int N) {
    int lane = threadIdx.x & 63;
    int node = blockIdx.x * 4 + (threadIdx.x >> 6);
    if (node >= N) return;
    int beg = rowptr[node], end = rowptr[node + 1];
    float s = 0.0f;
    for (int i = beg + lane; i < end; i += 64)
        s += __int_as_float(emeta[i].y);
    #pragma unroll
    for (int off = 32; off > 0; off >>= 1) s += __shfl_xor(s, off, 64);
    float lw = flags[node] ? 0.0f : 1.0f;
    float d = s + lw;
    float di = (d > 0.0f) ? rsqrtf(fmaxf(d, EPS_F)) : 0.0f;
    if (lane == 0) dinfo[node] = make_float2(di, lw);
}

// ---------------------------------------------------------------------------
// Compaction: split batch positions into user list / item list.
// ---------------------------------------------------------------------------
__global__ __launch_bounds__(256) void k_classify(const int* __restrict__ batch_nodes,
                                                  int* __restrict__ ucnt, int* __restrict__ icnt,
                                                  int* __restrict__ upos, int* __restrict__ ubid,
                                                  int* __restrict__ ipos, int* __restrict__ iit,
                                                  int N) {
    int i = blockIdx.x * 256 + threadIdx.x;
    if (i >= N) return;
    int idx = batch_nodes[i];
    if (idx < NUM_USERS_C) {
        int p = atomicAdd(ucnt, 1);       // wave-coalesced by compiler
        upos[p] = i; ubid[p] = idx;
    } else {
        int p = atomicAdd(icnt, 1);
        ipos[p] = i; iit[p] = idx - NUM_USERS_C;
    }
}

// ---------------------------------------------------------------------------
// User features: wave per user (lane = dim). Pure gather + l2norm.
// Writes only x~0 = dinv * x0.
// ---------------------------------------------------------------------------
__global__ __launch_bounds__(256) void k_feat_user(
    const int* __restrict__ ucnt, const int* __restrict__ upos, const int* __restrict__ ubid,
    const float* __restrict__ user_emb, const float2* __restrict__ dinfo,
    float* __restrict__ xt)
{
    int lane = threadIdx.x & 63;
    int gwid = blockIdx.x * 4 + (threadIdx.x >> 6);
    int stride = gridDim.x * 4;
    int uc = *ucnt;
    for (int u = gwid; u < uc; u += stride) {
        int n = upos[u];                   // wave-uniform
        int id = ubid[u];
        float val = user_emb[(size_t)id * 64 + lane];
        float ss = val * val;
        #pragma unroll
        for (int off = 32; off > 0; off >>= 1) ss += __shfl_xor(ss, off, 64);
        float scale = 1.0f / fmaxf(sqrtf(ss), EPS_F);
        xt[(size_t)n * 64 + lane] = dinfo[n].x * val * scale;
    }
}

// ---------------------------------------------------------------------------
// Item features: lane = dim, 8 items per wave. Broadcast-free inner loop:
//  - W transposed in LDS (WsT[d][k], XOR-swizzled) -> each lane reads its own
//    4 consecutive W values per ds_read_b128 (8-quad spread = LDS floor).
//  - group features staged in per-wave LDS scratch, read back wave-uniform
//    as ds_read_b128 (HW broadcast, 4 k per instr). Zero readlane/shfl.
// ---------------------------------------------------------------------------
__device__ __forceinline__ int wswz(int d, int k) {
    // float-index swizzle: byte ^= (d&7)<<4  ==  fidx ^= (d&7)<<2
    return (d * 128 + k) ^ ((d & 7) << 2);
}

__global__ __launch_bounds__(256) void k_feat_item(
    const int* __restrict__ icnt, const int* __restrict__ ipos, const int* __restrict__ iit,
    const float* __restrict__ artist_emb, const float* __restrict__ album_emb,
    const float* __restrict__ audio_emb,
    const int* __restrict__ artist_ids, const int* __restrict__ album_ids,
    const float* __restrict__ proj_w, const float* __restrict__ proj_b,
    const float2* __restrict__ dinfo,
    float* __restrict__ xt)
{
    __shared__ __align__(16) float WsT[64 * 128];   // [d][k], swizzled, 32 KB
    __shared__ __align__(16) float stg[4][8 * 128]; // [wave][item][k], 16 KB

    // Load + transpose W. proj_w is [128][64] row-major: elem (k,d) at k*64+d.
    for (int i = threadIdx.x; i < 128 * 64; i += blockDim.x) {
        int k = i >> 6, d = i & 63;
        WsT[wswz(d, k)] = proj_w[i];
    }
    __syncthreads();

    const int lane = threadIdx.x & 63;
    const int wid = threadIdx.x >> 6;
    const int ic = *icnt;
    const int ngroups = (ic + 7) / 8;
    const int gstride = gridDim.x * 4;
    const float bias = proj_b[lane];
    float* __restrict__ fs = stg[wid];

    for (int g = blockIdx.x * 4 + wid; g < ngroups; g += gstride) {
        int base = g * 8;
        int cnt8 = min(8, ic - base);
        int nn[8];
        #pragma unroll
        for (int j = 0; j < 8; ++j) {
            int jj = (j < cnt8) ? base + j : base;   // dup first item for dead slots
            int it = iit[jj];                        // wave-uniform s_load
            nn[j] = ipos[jj];
            int aid = artist_ids[it];
            int bid = album_ids[it];
            float vlo = audio_emb[(size_t)it * 64 + lane];
            float vhi = 0.5f * (artist_emb[(size_t)aid * 64 + lane] +
                                album_emb[(size_t)bid * 64 + lane]);
            fs[j * 128 + lane] = vlo;                // coalesced ds_write
            fs[j * 128 + 64 + lane] = vhi;
        }

        float acc[8];
        #pragma unroll
        for (int j = 0; j < 8; ++j) acc[j] = bias;

        #pragma unroll
        for (int k = 0; k < 128; k += 4) {
            float4 w = *(const float4*)&WsT[wswz(lane, k)];  // per-lane b128
            #pragma unroll
            for (int j = 0; j < 8; ++j) {
                float4 f = *(const float4*)&fs[j * 128 + k]; // uniform broadcast
                acc[j] = fmaf(f.x, w.x, acc[j]);
                acc[j] = fmaf(f.y, w.y, acc[j]);
                acc[j] = fmaf(f.z, w.z, acc[j]);
                acc[j] = fmaf(f.w, w.w, acc[j]);
            }
        }

        #pragma unroll
        for (int j = 0; j < 8; ++j) {
            if (j < cnt8) {
                float val = acc[j];
                float ss = val * val;
                #pragma unroll
                for (int off = 32; off > 0; off >>= 1) ss += __shfl_xor(ss, off, 64);
                float scale = 1.0f / fmaxf(sqrtf(ss), EPS_F);
                int n = nn[j];
                xt[(size_t)n * 64 + lane] = dinfo[n].x * val * scale;
            }
        }
    }
}

// ---------------------------------------------------------------------------
// CSR propagation over x~ = dinv*x. Since every layer's x~ carries the SAME
// per-node factor dinv, and the output is l2-normalized per node, we never
// need acc = sum(x_l): l2norm(sum x~_l) == l2norm(sum x_l). Props write only
// x~; prop2 folds the running per-node sum (coalesced own-row, race-free).
// ---------------------------------------------------------------------------
__device__ __forceinline__ float prop_edges(
    const int* __restrict__ rowptr, const int2* __restrict__ emeta,
    const float* __restrict__ xs, int node, int lane)
{
    int beg = rowptr[node], end = rowptr[node + 1];
    float a = 0.0f;
    for (int base = beg; base < end; base += 64) {
        int chunk = min(64, end - base);
        int2 m = make_int2(0, 0);
        if (lane < chunk) m = emeta[base + lane];   // coalesced 8B/lane
        int j = 0;
        for (; j + 16 <= chunk; j += 16) {          // 16 loads in flight
            int rr[16]; float ww[16], vv[16];
            #pragma unroll
            for (int t = 0; t < 16; t++) {
                rr[t] = __shfl(m.x, j + t);
                ww[t] = __int_as_float(__shfl(m.y, j + t));
            }
            #pragma unroll
            for (int t = 0; t < 16; t++) vv[t] = xs[(size_t)rr[t] * 64 + lane];
            #pragma unroll
            for (int t = 0; t < 16; t++) a = fmaf(ww[t], vv[t], a);
        }
        for (; j + 8 <= chunk; j += 8) {
            int rr[8]; float ww[8], vv[8];
            #pragma unroll
            for (int t = 0; t < 8; t++) {
                rr[t] = __shfl(m.x, j + t);
                ww[t] = __int_as_float(__shfl(m.y, j + t));
            }
            #pragma unroll
            for (int t = 0; t < 8; t++) vv[t] = xs[(size_t)rr[t] * 64 + lane];
            #pragma unroll
            for (int t = 0; t < 8; t++) a = fmaf(ww[t], vv[t], a);
        }
        for (; j < chunk; j++) {
            int r = __shfl(m.x, j); float wv = __int_as_float(__shfl(m.y, j));
            a = fmaf(wv, xs[(size_t)r * 64 + lane], a);
        }
    }
    return a;
}

// Layer 1: read x~0, write x~1 only.
__global__ __launch_bounds__(256) void k_prop1(
    const int* __restrict__ rowptr, const int2* __restrict__ emeta,
    const float2* __restrict__ dinfo,
    const float* __restrict__ xs, float* __restrict__ xd, int N)
{
    int lane = threadIdx.x & 63;
    int node = blockIdx.x * 4 + (threadIdx.x >> 6);
    if (node >= N) return;
    float2 dn = dinfo[node];
    float self = xs[(size_t)node * 64 + lane];
    float t = dn.y * self + prop_edges(rowptr, emeta, xs, node, lane);
    xd[(size_t)node * 64 + lane] = (dn.x * dn.x) * t;   // x~1
}

// Layer 2: read x~1, write x~2; fold psum = x~0 + x~1 + x~2 into x0 buffer.
__global__ __launch_bounds__(256) void k_prop2(
    const int* __restrict__ rowptr, const int2* __restrict__ emeta,
    const float2* __restrict__ dinfo,
    const float* __restrict__ xs, float* __restrict__ xd,
    float* __restrict__ ps, int N)
{
    int lane = threadIdx.x & 63;
    int node = blockIdx.x * 4 + (threadIdx.x >> 6);
    if (node >= N) return;
    float2 dn = dinfo[node];
    size_t o = (size_t)node * 64 + lane;
    float s1 = xs[o];                                    // x~1 own row
    float t = dn.y * s1 + prop_edges(rowptr, emeta, xs, node, lane);
    float x2t = (dn.x * dn.x) * t;                       // x~2
    xd[o] = x2t;
    ps[o] = ps[o] + s1 + x2t;                            // x~0 + x~1 + x~2
}

// Layer 3: read x~2, add x~3 to psum, l2norm, write out.
__global__ __launch_bounds__(256) void k_prop_final(
    const int* __restrict__ rowptr, const int2* __restrict__ emeta,
    const float2* __restrict__ dinfo,
    const float* __restrict__ xs, const float* __restrict__ ps,
    float* __restrict__ out, int N)
{
    int lane = threadIdx.x & 63;
    int node = blockIdx.x * 4 + (threadIdx.x >> 6);
    if (node >= N) return;
    float2 dn = dinfo[node];
    size_t o = (size_t)node * 64 + lane;
    float s2 = xs[o];                                    // x~2 own row
    float t = dn.y * s2 + prop_edges(rowptr, emeta, xs, node, lane);
    float x3t = (dn.x * dn.x) * t;                       // x~3
    float v = ps[o] + x3t;                               // dinv_n * sum(x_l)
    float ss = v * v;
    #pragma unroll
    for (int off = 32; off > 0; off >>= 1) ss += __shfl_xor(ss, off, 64);
    float scale = 1.0f / fmaxf(sqrtf(ss), EPS_F);
    out[o] = v * scale;                                  // scale-invariant
}

// ---------------------------------------------------------------------------
extern "C" void kernel_launch(void* const* d_in, const int* in_sizes, int n_in,
                              void* d_out, int out_size, void* d_ws, size_t ws_size,
                              hipStream_t stream) {
    const int*   batch_nodes = (const int*)d_in[0];
    const int*   edge_index  = (const int*)d_in[1];
    const float* edge_w      = (const float*)d_in[2];
    const float* user_emb    = (const float*)d_in[3];
    const float* artist_emb  = (const float*)d_in[4];
    const float* album_emb   = (const float*)d_in[5];
    const float* audio_emb   = (const float*)d_in[6];
    const int*   artist_ids  = (const int*)d_in[7];
    const int*   album_ids   = (const int*)d_in[8];
    const float* proj_w      = (const float*)d_in[9];
    const float* proj_b      = (const float*)d_in[10];

    const int N = in_sizes[0];
    const int E = in_sizes[2];
    const int* row = edge_index;
    const int* col = edge_index + E;
    float* out = (float*)d_out;        // scratch for x~1, then final output

    const int NB = (N + 255) / 256;

    // workspace carve-up
    char* ws = (char*)d_ws;
    int*    flags  = (int*)ws;    ws += (size_t)N * sizeof(int);
    int*    cnt    = (int*)ws;    ws += (size_t)N * sizeof(int);
    int*    rowptr = (int*)ws;    ws += (size_t)(N + 1) * sizeof(int);
    int*    bsum   = (int*)ws;    ws += (size_t)NB * sizeof(int);
    int*    boff   = (int*)ws;    ws += (size_t)NB * sizeof(int);
    int*    cnts2  = (int*)ws;    ws += 2 * sizeof(int);   // {ucnt, icnt}
    ws = (char*)(((uintptr_t)ws + 15) & ~(uintptr_t)15);
    float2* dinfo  = (float2*)ws; ws += (size_t)N * sizeof(float2);
    int2*   emeta  = (int2*)ws;   ws += (size_t)E * sizeof(int2);
    float*  xA     = (float*)ws;  ws += (size_t)N * 64 * sizeof(float);  // x~0 -> psum
    float*  xB     = (float*)ws;  ws += (size_t)N * 64 * sizeof(float);  // x~2

    // Aliases inside xB (dead before k_prop2 writes xB):
    //  slot: live edgeprep -> scatter;  lists: live classify -> feat kernels.
    int* slot = (int*)xB;
    int* upos = (int*)xB;
    int* ubid = upos + N;
    int* ipos = ubid + N;
    int* iit  = ipos + N;

    hipMemsetAsync(flags, 0, (size_t)N * sizeof(int), stream);
    hipMemsetAsync(cnt, 0, (size_t)N * sizeof(int), stream);

    const int TB = 256;

    k_edgeprep<<<(E + TB - 1) / TB, TB, 0, stream>>>(row, col, flags, cnt, slot, E);
    k_blocksum<<<NB, 256, 0, stream>>>(cnt, bsum, N);
    k_scanbsum<<<1, 1024, 0, stream>>>(bsum, boff, rowptr, NB, N);
    k_rowptr<<<NB, 256, 0, stream>>>(cnt, boff, rowptr, N);
    k_scatter<<<(E + TB - 1) / TB, TB, 0, stream>>>(row, col, edge_w, slot,
                                                    rowptr, emeta, E);

    int pblocks = (N + 3) / 4;  // 4 waves (nodes) per 256-thread block
    k_deg<<<pblocks, 256, 0, stream>>>(rowptr, emeta, flags, dinfo, N);

    // slot[] is dead now; reuse xB space for the compaction lists.
    hipMemsetAsync(cnts2, 0, 2 * sizeof(int), stream);
    k_classify<<<NB, 256, 0, stream>>>(batch_nodes, &cnts2[0], &cnts2[1],
                                       upos, ubid, ipos, iit, N);

    k_feat_user<<<1024, 256, 0, stream>>>(&cnts2[0], upos, ubid, user_emb, dinfo, xA);
    k_feat_item<<<2048, 256, 0, stream>>>(&cnts2[1], ipos, iit,
                                          artist_emb, album_emb, audio_emb,
                                          artist_ids, album_ids, proj_w, proj_b,
                                          dinfo, xA);

    // x~0 in xA; prop1 -> x~1 in out; prop2 -> x~2 in xB, psum in xA; final -> out
    k_prop1<<<pblocks, 256, 0, stream>>>(rowptr, emeta, dinfo, xA, out, N);
    k_prop2<<<pblocks, 256, 0, stream>>>(rowptr, emeta, dinfo, out, xB, xA, N);
    k_prop_final<<<pblocks, 256, 0, stream>>>(rowptr, emeta, dinfo, xB, xA, out, N);
}